// Round 1
// baseline (191.691 us; speedup 1.0000x reference)
//
#include <hip/hip_runtime.h>
#include <math.h>

typedef __bf16 bf16_t;
typedef __bf16 v8bf __attribute__((ext_vector_type(8)));
typedef __bf16 v4bf __attribute__((ext_vector_type(4)));
typedef float  v4f  __attribute__((ext_vector_type(4)));

#define AS1 __attribute__((address_space(1)))
#define AS3 __attribute__((address_space(3)))

// async global->LDS 16B copy; LDS dest = wave-uniform base + lane*16
static __device__ __forceinline__ void load_lds16(const bf16_t* g, bf16_t* l) {
    __builtin_amdgcn_global_load_lds((AS1 void*)const_cast<bf16_t*>(g),
                                     (AS3 void*)l, 16, 0, 0);
}

// sin/cos via native HW ops with explicit revolution reduction (no libcall)
static __device__ __forceinline__ void fast_sincos(float ang, float* sn, float* cs) {
    float rv = ang * 0.15915494309189535f;
    rv -= floorf(rv);
    const float a = rv * 6.283185307179586f;
    *sn = __sinf(a);
    *cs = __cosf(a);
}

// ---------------------------------------------------------------------------
// Kernel 0: fp32 -> bf16 for h + 4 weights. 8M elems, 8/thread.
// ---------------------------------------------------------------------------
__global__ __launch_bounds__(256) void cvt_fp32_bf16(
    const float* __restrict__ h,  const float* __restrict__ wq,
    const float* __restrict__ wk, const float* __restrict__ wv,
    const float* __restrict__ wo,
    bf16_t* __restrict__ hb,  bf16_t* __restrict__ wqb,
    bf16_t* __restrict__ wkb, bf16_t* __restrict__ wvb,
    bf16_t* __restrict__ wob)
{
    const size_t HM = (size_t)4 << 20;
    const size_t i8 = ((size_t)blockIdx.x * 256 + threadIdx.x) * 8;
    const float* src; bf16_t* dst; size_t off;
    if (i8 < HM) { src = h; dst = hb; off = i8; }
    else {
        const size_t r = (i8 - HM) >> 20;
        off = (i8 - HM) & (((size_t)1 << 20) - 1);
        src = (r == 0) ? wq  : (r == 1) ? wk  : (r == 2) ? wv  : wo;
        dst = (r == 0) ? wqb : (r == 1) ? wkb : (r == 2) ? wvb : wob;
    }
    const float4 a = *(const float4*)(src + off);
    const float4 b = *(const float4*)(src + off + 4);
    v8bf o;
    o[0]=(bf16_t)a.x; o[1]=(bf16_t)a.y; o[2]=(bf16_t)a.z; o[3]=(bf16_t)a.w;
    o[4]=(bf16_t)b.x; o[5]=(bf16_t)b.y; o[6]=(bf16_t)b.z; o[7]=(bf16_t)b.w;
    *(v8bf*)(dst + off) = o;
}

// ---------------------------------------------------------------------------
// Kernel 1: QKV = h @ [wq|wk|wv]^T, fused RoPE on Q,K (inline transcendentals).
// All-bf16 inputs, global_load_lds staging. Q,K: [32][2048][64];
// V TRANSPOSED: [32][64][2048]. Epilogue stores wave-coalesced v8bf via LDS.
// ---------------------------------------------------------------------------
__global__ __launch_bounds__(256) void qkv_gemm_rope(
    const bf16_t* __restrict__ A,   // h bf16 [4096][1024]
    const bf16_t* __restrict__ wq,
    const bf16_t* __restrict__ wk,
    const bf16_t* __restrict__ wv,
    bf16_t* __restrict__ qo, bf16_t* __restrict__ ko, bf16_t* __restrict__ vo)
{
    __shared__ __align__(16) bf16_t smem[17408];
    bf16_t* As = smem;
    bf16_t* Bs = smem + 4096;

    const int tid = threadIdx.x;
    const int n0  = blockIdx.x * 128;
    const int m0  = blockIdx.y * 128;
    const int sel = n0 >> 10;               // 0=Q 1=K 2=V
    const bf16_t* W = (sel == 0) ? wq : (sel == 1) ? wk : wv;
    const int wr0 = n0 & 1023;

    const int wave = tid >> 6;
    const int lane = tid & 63;
    const int l16  = lane & 15;
    const int quad = lane >> 4;
    const int wrow = (wave >> 1) * 64;
    const int wcol = (wave & 1) * 64;

    v4f acc[4][4];
    #pragma unroll
    for (int i = 0; i < 4; ++i)
        #pragma unroll
        for (int j = 0; j < 4; ++j) acc[i][j] = (v4f)(0.0f);

    for (int kt = 0; kt < 32; ++kt) {
        const int k0 = kt * 32;
        #pragma unroll
        for (int rep = 0; rep < 2; ++rep) {
            const int c   = rep * 256 + tid;
            const int row = c >> 2;
            const int col = (c & 3) * 8;
            load_lds16(A + (size_t)(m0 + row) * 1024 + k0 + col, &As[c * 8]);
            load_lds16(W + (size_t)(wr0 + row) * 1024 + k0 + col, &Bs[c * 8]);
        }
        __syncthreads();

        v8bf af[4], bfb[4];
        #pragma unroll
        for (int i = 0; i < 4; ++i) {
            af[i]  = *(const v8bf*)&As[(wrow + i * 16 + l16) * 32 + quad * 8];
            bfb[i] = *(const v8bf*)&Bs[(wcol + i * 16 + l16) * 32 + quad * 8];
        }
        #pragma unroll
        for (int i = 0; i < 4; ++i)
            #pragma unroll
            for (int j = 0; j < 4; ++j)
                acc[i][j] = __builtin_amdgcn_mfma_f32_16x16x32_bf16(
                    af[i], bfb[j], acc[i][j], 0, 0, 0);
        __syncthreads();
    }

    bf16_t* Ls = smem + wave * 4352;          // [64][stride 68]
    const int bq     = (m0 + wrow) >> 11;
    const int hd     = ((n0 + wcol) >> 6) & 15;
    const int t_base = (m0 + wrow) & 2047;

    if (sel < 2) {
        bf16_t* OUT = (sel == 0) ? qo : ko;
        #pragma unroll
        for (int i = 0; i < 4; ++i) {
            #pragma unroll
            for (int j = 0; j < 4; ++j) {
                #pragma unroll
                for (int r = 0; r < 4; ++r) {
                    const int mrow = i * 16 + quad * 4 + r;
                    const int dcol = j * 16 + l16;
                    float v = acc[i][j][r];
                    const float vp = __shfl_xor(v, 1);   // pair d^1 = lane^1
                    const int t  = t_base + mrow;
                    const int kk = dcol >> 1;
                    const float freq = exp2f((float)kk * -0.4152410118609203f);
                    float sn, cs;
                    fast_sincos((float)t * freq, &sn, &cs);
                    v = ((dcol & 1) == 0) ? (cs * v - sn * vp) : (sn * vp + cs * v);
                    Ls[mrow * 68 + dcol] = (bf16_t)v;
                }
            }
        }
        #pragma unroll
        for (int s = 0; s < 8; ++s) {
            const int row = s * 8 + (lane >> 3);
            const int off = (lane & 7) * 8;
            const v8bf vv = *(const v8bf*)&Ls[row * 68 + off];
            *(v8bf*)(OUT + (((size_t)(bq * 16 + hd) * 2048) + t_base + row) * 64 + off) = vv;
        }
    } else {
        #pragma unroll
        for (int i = 0; i < 4; ++i)
            #pragma unroll
            for (int j = 0; j < 4; ++j) {
                v4bf p;
                #pragma unroll
                for (int r = 0; r < 4; ++r) p[r] = (bf16_t)acc[i][j][r];
                *(v4bf*)&Ls[(j * 16 + l16) * 68 + i * 16 + quad * 4] = p;
            }
        #pragma unroll
        for (int s = 0; s < 8; ++s) {
            const int drow = s * 8 + (lane >> 3);
            const int off  = (lane & 7) * 8;
            const v8bf vv = *(const v8bf*)&Ls[drow * 68 + off];
            *(v8bf*)(vo + (((size_t)(bq * 16 + hd) * 64) + drow) * 2048 + t_base + off) = vv;
        }
    }
}

// ---------------------------------------------------------------------------
// Kernel 2: causal flash attention — S^T core, REWORKED:
//  * 32 Q rows per wave (two 16-row fragment groups) -> each K/V LDS frag read
//    feeds 2 MFMAs (20 b128 reads per 36 MFMAs vs 18/18 before)
//  * stride-64 LDS rows + XOR swizzle (byte ^= (row&7)<<4) -> bank-conflict-free
//    fragment reads, LDS 55.3KB -> 48KB (3 blocks/CU)
//  * defer-max (T13, THR=8 in exp2 domain): skip O/l rescale when max growth
//    small; P bounded by 2^8, exact after final 1/l normalization
//  * 256-thread blocks, grid 512, same XCD-grouped + CU-sum-balanced mapping
// ---------------------------------------------------------------------------
__global__ __launch_bounds__(256, 3) void attn_mfma(
    const bf16_t* __restrict__ qg,
    const bf16_t* __restrict__ kg,
    const bf16_t* __restrict__ vtg,
    bf16_t* __restrict__ og)
{
    __shared__ __align__(16) bf16_t Ks[2][4096];   // [64 k][64 d] swizzled
    __shared__ __align__(16) bf16_t Vs[2][4096];   // [64 d][64 k] swizzled
    __shared__ __align__(16) bf16_t Ps[8][1024];   // [wave*2+g][16 q][64 k] swizzled

    const int tid  = threadIdx.x;          // 0..255
    const int wave = tid >> 6;             // 0..3
    const int lane = tid & 63;
    const int l16  = lane & 15;
    const int quad = lane >> 4;

    const int i  = blockIdx.x;             // 0..511
    const int tt = i >> 3;                 // 0..63
    const int u  = tt & 15;
    const int g4 = tt >> 4;                // 0..3
    const int q128 = (((g4 + 1) >> 1) & 1) ? (15 - u) : u;
    const int bh = (i & 7) * 4 + g4;
    const int b = bh >> 4, hh = bh & 15;

    const bf16_t* Kb = kg  + (size_t)bh * 2048 * 64;
    const bf16_t* Vb = vtg + (size_t)bh * 64 * 2048;

    const int qrow0   = q128 * 128 + wave * 32;    // wave's first Q row
    const int ktmax_w = 2 * q128 + (wave >> 1);    // wave's last (=diag) K-tile
    const int ktmax_b = 2 * q128 + 1;              // block's last K-tile

    const int sw  = (l16 & 7) << 4;        // XOR swizzle for rows == l16 (mod 8)
    const int cb0 = (quad << 4) ^ sw;      // frag read col byte (first 64B half)

    // Q B-frags, 2 row-groups; fold 1/8 * log2(e) (softmax runs in exp2 domain)
    v8bf qf[2][2];
    #pragma unroll
    for (int g = 0; g < 2; ++g) {
        const bf16_t* qrow = qg + ((size_t)bh * 2048 + qrow0 + g * 16 + l16) * 64;
        qf[g][0] = *(const v8bf*)(qrow + quad * 8);
        qf[g][1] = *(const v8bf*)(qrow + 32 + quad * 8);
        #pragma unroll
        for (int e = 0; e < 8; ++e) {
            qf[g][0][e] = (bf16_t)((float)qf[g][0][e] * 0.18033688011112042f);
            qf[g][1][e] = (bf16_t)((float)qf[g][1][e] * 0.18033688011112042f);
        }
    }

    // all-ones A-frag for the l-sum MFMA
    v8bf ones1;
    #pragma unroll
    for (int e = 0; e < 8; ++e) ones1[e] = (bf16_t)1.0f;

    float m_r[2] = {-1e30f, -1e30f};
    v4f l_acc[2];
    l_acc[0] = (v4f)(0.0f); l_acc[1] = (v4f)(0.0f);
    v4f o_acc[2][4];
    #pragma unroll
    for (int g = 0; g < 2; ++g)
        #pragma unroll
        for (int d = 0; d < 4; ++d) o_acc[g][d] = (v4f)(0.0f);

    // staging geometry: 256 threads x 32B cover one 8KB tile (K and V each)
    const int srow = tid >> 2;             // 0..63
    const int sc   = (tid & 3) << 4;       // elem col 0/16/32/48
    const int swr  = (srow & 7) << 4;
    const int sb0  = (sc * 2) ^ swr;       // swizzled byte cols
    const int sb1  = (sc * 2 + 16) ^ swr;

    // stage tile 0 into buffer 0
    {
        const bf16_t* kp = Kb + (size_t)srow * 64 + sc;
        const bf16_t* vp = Vb + (size_t)srow * 2048 + sc;
        char* kd = (char*)Ks[0] + (srow << 7);
        char* vd = (char*)Vs[0] + (srow << 7);
        *(v8bf*)(kd + sb0) = *(const v8bf*)kp;
        *(v8bf*)(kd + sb1) = *(const v8bf*)(kp + 8);
        *(v8bf*)(vd + sb0) = *(const v8bf*)vp;
        *(v8bf*)(vd + sb1) = *(const v8bf*)(vp + 8);
    }

    for (int kt = 0; kt <= ktmax_b; ++kt) {
        const int cur = kt & 1;
        const int nxt = cur ^ 1;
        __syncthreads();   // buf[cur] complete; prior reads of buf[nxt] done

        // issue prefetch of tile kt+1 (vmcnt wait deferred to the ds_write)
        v8bf k0, k1, v0, v1;
        if (kt < ktmax_b) {
            const bf16_t* kp = Kb + ((size_t)(kt + 1) * 64 + srow) * 64 + sc;
            const bf16_t* vp = Vb + (size_t)srow * 2048 + (kt + 1) * 64 + sc;
            k0 = *(const v8bf*)kp; k1 = *(const v8bf*)(kp + 8);
            v0 = *(const v8bf*)vp; v1 = *(const v8bf*)(vp + 8);
        }

        if (kt <= ktmax_w) {
            // ---- S^T tiles for both Q-groups (K-frags shared) ----
            const char* ksc = (const char*)Ks[cur];
            v4f s[2][4];
            #pragma unroll
            for (int g = 0; g < 2; ++g)
                #pragma unroll
                for (int kblk = 0; kblk < 4; ++kblk) s[g][kblk] = (v4f)(0.0f);
            #pragma unroll
            for (int kblk = 0; kblk < 4; ++kblk) {
                const char* kr = ksc + ((kblk * 16 + l16) << 7);
                const v8bf kf0 = *(const v8bf*)(kr + cb0);
                const v8bf kf1 = *(const v8bf*)(kr + (cb0 ^ 64));
                s[0][kblk] = __builtin_amdgcn_mfma_f32_16x16x32_bf16(
                    kf0, qf[0][0], s[0][kblk], 0, 0, 0);
                s[1][kblk] = __builtin_amdgcn_mfma_f32_16x16x32_bf16(
                    kf0, qf[1][0], s[1][kblk], 0, 0, 0);
                s[0][kblk] = __builtin_amdgcn_mfma_f32_16x16x32_bf16(
                    kf1, qf[0][1], s[0][kblk], 0, 0, 0);
                s[1][kblk] = __builtin_amdgcn_mfma_f32_16x16x32_bf16(
                    kf1, qf[1][1], s[1][kblk], 0, 0, 0);
            }

            if (kt == ktmax_w) {   // causal mask only on the diagonal tile
                #pragma unroll
                for (int g = 0; g < 2; ++g) {
                    const int qglb = qrow0 + g * 16 + l16;
                    #pragma unroll
                    for (int kblk = 0; kblk < 4; ++kblk)
                        #pragma unroll
                        for (int r = 0; r < 4; ++r)
                            if (kt * 64 + kblk * 16 + quad * 4 + r > qglb)
                                s[g][kblk][r] = -1e30f;
                }
            }

            // ---- online softmax (exp2 domain), defer-max rescale ----
            #pragma unroll
            for (int g = 0; g < 2; ++g) {
                float mx = -1e30f;
                #pragma unroll
                for (int kblk = 0; kblk < 4; ++kblk)
                    #pragma unroll
                    for (int r = 0; r < 4; ++r) mx = fmaxf(mx, s[g][kblk][r]);
                mx = fmaxf(mx, __shfl_xor(mx, 16));
                mx = fmaxf(mx, __shfl_xor(mx, 32));
                if (!__all(mx - m_r[g] <= 8.0f)) {
                    const float mn = fmaxf(m_r[g], mx);
                    const float a  = exp2f(m_r[g] - mn);
                    m_r[g] = mn;
                    l_acc[g] *= a;
                    #pragma unroll
                    for (int d = 0; d < 4; ++d) o_acc[g][d] *= a;
                }
                char* psc = (char*)Ps[wave * 2 + g] + (l16 << 7);
                #pragma unroll
                for (int kblk = 0; kblk < 4; ++kblk) {
                    v4bf p;
                    #pragma unroll
                    for (int r = 0; r < 4; ++r)
                        p[r] = (bf16_t)exp2f(s[g][kblk][r] - m_r[g]);
                    *(v4bf*)(psc + (((kblk << 5) + (quad << 3)) ^ sw)) = p;
                }
            }

            // ---- O^T += V^T P^T (V-frags shared by both groups); l via ones ----
            const char* vsc = (const char*)Vs[cur];
            v8bf pf[2][2];
            #pragma unroll
            for (int g = 0; g < 2; ++g) {
                const char* psc = (const char*)Ps[wave * 2 + g] + (l16 << 7);
                pf[g][0] = *(const v8bf*)(psc + cb0);
                pf[g][1] = *(const v8bf*)(psc + (cb0 ^ 64));
            }
            #pragma unroll
            for (int dblk = 0; dblk < 4; ++dblk) {
                const char* vr = vsc + ((dblk * 16 + l16) << 7);
                const v8bf vf0 = *(const v8bf*)(vr + cb0);
                const v8bf vf1 = *(const v8bf*)(vr + (cb0 ^ 64));
                o_acc[0][dblk] = __builtin_amdgcn_mfma_f32_16x16x32_bf16(
                    vf0, pf[0][0], o_acc[0][dblk], 0, 0, 0);
                o_acc[1][dblk] = __builtin_amdgcn_mfma_f32_16x16x32_bf16(
                    vf0, pf[1][0], o_acc[1][dblk], 0, 0, 0);
                o_acc[0][dblk] = __builtin_amdgcn_mfma_f32_16x16x32_bf16(
                    vf1, pf[0][1], o_acc[0][dblk], 0, 0, 0);
                o_acc[1][dblk] = __builtin_amdgcn_mfma_f32_16x16x32_bf16(
                    vf1, pf[1][1], o_acc[1][dblk], 0, 0, 0);
            }
            l_acc[0] = __builtin_amdgcn_mfma_f32_16x16x32_bf16(
                ones1, pf[0][0], l_acc[0], 0, 0, 0);
            l_acc[0] = __builtin_amdgcn_mfma_f32_16x16x32_bf16(
                ones1, pf[0][1], l_acc[0], 0, 0, 0);
            l_acc[1] = __builtin_amdgcn_mfma_f32_16x16x32_bf16(
                ones1, pf[1][0], l_acc[1], 0, 0, 0);
            l_acc[1] = __builtin_amdgcn_mfma_f32_16x16x32_bf16(
                ones1, pf[1][1], l_acc[1], 0, 0, 0);
        }

        // write next tile into the other buffer (overlaps others' compute)
        if (kt < ktmax_b) {
            char* kd = (char*)Ks[nxt] + (srow << 7);
            char* vd = (char*)Vs[nxt] + (srow << 7);
            *(v8bf*)(kd + sb0) = k0;
            *(v8bf*)(kd + sb1) = k1;
            *(v8bf*)(vd + sb0) = v0;
            *(v8bf*)(vd + sb1) = v1;
        }
    }

    // ---- epilogue: O^T col m=l16 -> og[b][t][hh*64+d], v4bf stores ----
    #pragma unroll
    for (int g = 0; g < 2; ++g) {
        const float inv_l = 1.0f / l_acc[g][0];   // all regs equal (ones-A rows)
        const size_t base = ((size_t)b * 2048 + qrow0 + g * 16 + l16) * 1024 + hh * 64;
        #pragma unroll
        for (int dblk = 0; dblk < 4; ++dblk) {
            v4bf o;
            #pragma unroll
            for (int r = 0; r < 4; ++r) o[r] = (bf16_t)(o_acc[g][dblk][r] * inv_l);
            *(v4bf*)(og + base + dblk * 16 + quad * 4) = o;
        }
    }
}

// ---------------------------------------------------------------------------
// Kernel 3: d_out(fp32) = og @ wo^T. 128x64 tiles, 512 blocks (2/CU).
// ---------------------------------------------------------------------------
__global__ __launch_bounds__(256) void out_gemm(
    const bf16_t* __restrict__ A,   // og [4096][1024] bf16
    const bf16_t* __restrict__ W,   // wob [1024][1024] bf16
    float* __restrict__ C)
{
    __shared__ __align__(16) float smemf[4352];
    bf16_t* As = (bf16_t*)smemf;        // [128][32]
    bf16_t* Bs = As + 4096;             // [64][32]

    const int tid = threadIdx.x;
    const int n0  = blockIdx.x * 64;
    const int m0  = blockIdx.y * 128;

    const int wave = tid >> 6;
    const int lane = tid & 63;
    const int l16  = lane & 15;
    const int quad = lane >> 4;
    const int wrow = (wave >> 1) * 64;
    const int wcol = (wave & 1) * 32;

    v4f acc[4][2];
    #pragma unroll
    for (int i = 0; i < 4; ++i)
        #pragma unroll
        for (int j = 0; j < 2; ++j) acc[i][j] = (v4f)(0.0f);

    for (int kt = 0; kt < 32; ++kt) {
        const int k0 = kt * 32;
        #pragma unroll
        for (int rep = 0; rep < 2; ++rep) {
            const int c   = rep * 256 + tid;
            const int row = c >> 2;
            const int col = (c & 3) * 8;
            load_lds16(A + (size_t)(m0 + row) * 1024 + k0 + col, &As[c * 8]);
        }
        {
            const int row = tid >> 2;
            const int col = (tid & 3) * 8;
            load_lds16(W + (size_t)(n0 + row) * 1024 + k0 + col, &Bs[tid * 8]);
        }
        __syncthreads();

        v8bf af[4], bfb[2];
        #pragma unroll
        for (int i = 0; i < 4; ++i)
            af[i]  = *(const v8bf*)&As[(wrow + i * 16 + l16) * 32 + quad * 8];
        #pragma unroll
        for (int j = 0; j < 2; ++j)
            bfb[j] = *(const v8bf*)&Bs[(wcol + j * 16 + l16) * 32 + quad * 8];
        #pragma unroll
        for (int i = 0; i < 4; ++i)
            #pragma unroll
            for (int j = 0; j < 2; ++j)
                acc[i][j] = __builtin_amdgcn_mfma_f32_16x16x32_bf16(
                    af[i], bfb[j], acc[i][j], 0, 0, 0);
        __syncthreads();
    }

    float* Lw = smemf + wave * 1088;
    #pragma unroll
    for (int half = 0; half < 2; ++half) {
        #pragma unroll
        for (int ii = 0; ii < 2; ++ii) {
            const int i = half * 2 + ii;
            #pragma unroll
            for (int j = 0; j < 2; ++j)
                #pragma unroll
                for (int r = 0; r < 4; ++r)
                    Lw[(ii * 16 + quad * 4 + r) * 34 + j * 16 + l16] = acc[i][j][r];
        }
        // same-wave LDS RAW: DS pipe in-order per wave
        #pragma unroll
        for (int s = 0; s < 8; ++s) {
            const int row = s * 4 + (lane >> 4);      // 0..31
            const float2 vv = *(const float2*)&Lw[row * 34 + l16 * 2];
            *(float2*)(C + (size_t)(m0 + wrow + half * 32 + row) * 1024
                         + n0 + wcol + l16 * 2) = vv;
        }
    }
}

// ---------------------------------------------------------------------------
extern "C" void kernel_launch(void* const* d_in, const int* in_sizes, int n_in,
                              void* d_out, int out_size, void* d_ws, size_t ws_size,
                              hipStream_t stream) {
    const float* h  = (const float*)d_in[0];
    const float* wq = (const float*)d_in[1];
    const float* wk = (const float*)d_in[2];
    const float* wv = (const float*)d_in[3];
    const float* wo = (const float*)d_in[4];

    const size_t NH = (size_t)4096 * 1024;   // 4M
    const size_t NW = (size_t)1024 * 1024;   // 1M

    bf16_t* hb  = (bf16_t*)d_ws;
    bf16_t* wqb = hb  + NH;
    bf16_t* wkb = wqb + NW;
    bf16_t* wvb = wkb + NW;
    bf16_t* wob = wvb + NW;
    bf16_t* qw  = wob + NW;                  // [32][2048][64]
    bf16_t* kw  = qw + NH;
    bf16_t* vw  = kw + NH;                   // [32][64][2048] (V^T)
    bf16_t* og  = hb;                        // alias: hb dead after qkv
    // total: 20M elems = 40 MB

    cvt_fp32_bf16<<<dim3(4096), dim3(256), 0, stream>>>(
        h, wq, wk, wv, wo, hb, wqb, wkb, wvb, wob);
    qkv_gemm_rope<<<dim3(24, 32), dim3(256), 0, stream>>>(
        hb, wqb, wkb, wvb, qw, kw, vw);
    attn_mfma<<<dim3(512), dim3(256), 0, stream>>>(qw, kw, vw, og);
    out_gemm<<<dim3(16, 32), dim3(256), 0, stream>>>(og, wob, (float*)d_out);
}

// Round 2
// 187.909 us; speedup vs baseline: 1.0201x; 1.0201x over previous
//
#include <hip/hip_runtime.h>
#include <math.h>

typedef __bf16 bf16_t;
typedef __bf16 v8bf __attribute__((ext_vector_type(8)));
typedef __bf16 v4bf __attribute__((ext_vector_type(4)));
typedef float  v4f  __attribute__((ext_vector_type(4)));

#define AS1 __attribute__((address_space(1)))
#define AS3 __attribute__((address_space(3)))

// async global->LDS 16B copy; LDS dest = wave-uniform base + lane*16
static __device__ __forceinline__ void load_lds16(const bf16_t* g, bf16_t* l) {
    __builtin_amdgcn_global_load_lds((AS1 void*)const_cast<bf16_t*>(g),
                                     (AS3 void*)l, 16, 0, 0);
}
static __device__ __forceinline__ void load_lds16b(const char* g, char* l) {
    __builtin_amdgcn_global_load_lds((AS1 void*)const_cast<char*>(g),
                                     (AS3 void*)l, 16, 0, 0);
}

// sin/cos via native HW ops with explicit revolution reduction (no libcall)
static __device__ __forceinline__ void fast_sincos(float ang, float* sn, float* cs) {
    float rv = ang * 0.15915494309189535f;
    rv -= floorf(rv);
    const float a = rv * 6.283185307179586f;
    *sn = __sinf(a);
    *cs = __cosf(a);
}

// ---------------------------------------------------------------------------
// Kernel 0: fp32 -> bf16 for h + 4 weights. 8M elems, 8/thread.
// ---------------------------------------------------------------------------
__global__ __launch_bounds__(256) void cvt_fp32_bf16(
    const float* __restrict__ h,  const float* __restrict__ wq,
    const float* __restrict__ wk, const float* __restrict__ wv,
    const float* __restrict__ wo,
    bf16_t* __restrict__ hb,  bf16_t* __restrict__ wqb,
    bf16_t* __restrict__ wkb, bf16_t* __restrict__ wvb,
    bf16_t* __restrict__ wob)
{
    const size_t HM = (size_t)4 << 20;
    const size_t i8 = ((size_t)blockIdx.x * 256 + threadIdx.x) * 8;
    const float* src; bf16_t* dst; size_t off;
    if (i8 < HM) { src = h; dst = hb; off = i8; }
    else {
        const size_t r = (i8 - HM) >> 20;
        off = (i8 - HM) & (((size_t)1 << 20) - 1);
        src = (r == 0) ? wq  : (r == 1) ? wk  : (r == 2) ? wv  : wo;
        dst = (r == 0) ? wqb : (r == 1) ? wkb : (r == 2) ? wvb : wob;
    }
    const float4 a = *(const float4*)(src + off);
    const float4 b = *(const float4*)(src + off + 4);
    v8bf o;
    o[0]=(bf16_t)a.x; o[1]=(bf16_t)a.y; o[2]=(bf16_t)a.z; o[3]=(bf16_t)a.w;
    o[4]=(bf16_t)b.x; o[5]=(bf16_t)b.y; o[6]=(bf16_t)b.z; o[7]=(bf16_t)b.w;
    *(v8bf*)(dst + off) = o;
}

// ---------------------------------------------------------------------------
// Kernel 1: QKV = h @ [wq|wk|wv]^T, fused RoPE on Q,K (inline transcendentals).
// All-bf16 inputs, global_load_lds staging. Q,K: [32][2048][64];
// V TRANSPOSED: [32][64][2048]. Epilogue stores wave-coalesced v8bf via LDS.
// ---------------------------------------------------------------------------
__global__ __launch_bounds__(256) void qkv_gemm_rope(
    const bf16_t* __restrict__ A,   // h bf16 [4096][1024]
    const bf16_t* __restrict__ wq,
    const bf16_t* __restrict__ wk,
    const bf16_t* __restrict__ wv,
    bf16_t* __restrict__ qo, bf16_t* __restrict__ ko, bf16_t* __restrict__ vo)
{
    __shared__ __align__(16) bf16_t smem[17408];
    bf16_t* As = smem;
    bf16_t* Bs = smem + 4096;

    const int tid = threadIdx.x;
    const int n0  = blockIdx.x * 128;
    const int m0  = blockIdx.y * 128;
    const int sel = n0 >> 10;               // 0=Q 1=K 2=V
    const bf16_t* W = (sel == 0) ? wq : (sel == 1) ? wk : wv;
    const int wr0 = n0 & 1023;

    const int wave = tid >> 6;
    const int lane = tid & 63;
    const int l16  = lane & 15;
    const int quad = lane >> 4;
    const int wrow = (wave >> 1) * 64;
    const int wcol = (wave & 1) * 64;

    v4f acc[4][4];
    #pragma unroll
    for (int i = 0; i < 4; ++i)
        #pragma unroll
        for (int j = 0; j < 4; ++j) acc[i][j] = (v4f)(0.0f);

    for (int kt = 0; kt < 32; ++kt) {
        const int k0 = kt * 32;
        #pragma unroll
        for (int rep = 0; rep < 2; ++rep) {
            const int c   = rep * 256 + tid;
            const int row = c >> 2;
            const int col = (c & 3) * 8;
            load_lds16(A + (size_t)(m0 + row) * 1024 + k0 + col, &As[c * 8]);
            load_lds16(W + (size_t)(wr0 + row) * 1024 + k0 + col, &Bs[c * 8]);
        }
        __syncthreads();

        v8bf af[4], bfb[4];
        #pragma unroll
        for (int i = 0; i < 4; ++i) {
            af[i]  = *(const v8bf*)&As[(wrow + i * 16 + l16) * 32 + quad * 8];
            bfb[i] = *(const v8bf*)&Bs[(wcol + i * 16 + l16) * 32 + quad * 8];
        }
        #pragma unroll
        for (int i = 0; i < 4; ++i)
            #pragma unroll
            for (int j = 0; j < 4; ++j)
                acc[i][j] = __builtin_amdgcn_mfma_f32_16x16x32_bf16(
                    af[i], bfb[j], acc[i][j], 0, 0, 0);
        __syncthreads();
    }

    bf16_t* Ls = smem + wave * 4352;          // [64][stride 68]
    const int bq     = (m0 + wrow) >> 11;
    const int hd     = ((n0 + wcol) >> 6) & 15;
    const int t_base = (m0 + wrow) & 2047;

    if (sel < 2) {
        bf16_t* OUT = (sel == 0) ? qo : ko;
        #pragma unroll
        for (int i = 0; i < 4; ++i) {
            #pragma unroll
            for (int j = 0; j < 4; ++j) {
                #pragma unroll
                for (int r = 0; r < 4; ++r) {
                    const int mrow = i * 16 + quad * 4 + r;
                    const int dcol = j * 16 + l16;
                    float v = acc[i][j][r];
                    const float vp = __shfl_xor(v, 1);   // pair d^1 = lane^1
                    const int t  = t_base + mrow;
                    const int kk = dcol >> 1;
                    const float freq = exp2f((float)kk * -0.4152410118609203f);
                    float sn, cs;
                    fast_sincos((float)t * freq, &sn, &cs);
                    v = ((dcol & 1) == 0) ? (cs * v - sn * vp) : (sn * vp + cs * v);
                    Ls[mrow * 68 + dcol] = (bf16_t)v;
                }
            }
        }
        #pragma unroll
        for (int s = 0; s < 8; ++s) {
            const int row = s * 8 + (lane >> 3);
            const int off = (lane & 7) * 8;
            const v8bf vv = *(const v8bf*)&Ls[row * 68 + off];
            *(v8bf*)(OUT + (((size_t)(bq * 16 + hd) * 2048) + t_base + row) * 64 + off) = vv;
        }
    } else {
        #pragma unroll
        for (int i = 0; i < 4; ++i)
            #pragma unroll
            for (int j = 0; j < 4; ++j) {
                v4bf p;
                #pragma unroll
                for (int r = 0; r < 4; ++r) p[r] = (bf16_t)acc[i][j][r];
                *(v4bf*)&Ls[(j * 16 + l16) * 68 + i * 16 + quad * 4] = p;
            }
        #pragma unroll
        for (int s = 0; s < 8; ++s) {
            const int drow = s * 8 + (lane >> 3);
            const int off  = (lane & 7) * 8;
            const v8bf vv = *(const v8bf*)&Ls[drow * 68 + off];
            *(v8bf*)(vo + (((size_t)(bq * 16 + hd) * 64) + drow) * 2048 + t_base + off) = vv;
        }
    }
}

// ---------------------------------------------------------------------------
// Kernel 2: causal flash attention — S^T core.
//  Round-2 geometry: 256 threads = 4 waves x 16 Q-rows = 64 Q-rows/block,
//  grid 1024 (32 bh x 32 q-tiles) -> 4096 waves total, 4 blocks/CU resident
//  (LDS 40KB), zero idle-wave iterations (diag tile == last tile for all
//  waves), per-CU iteration sum exactly balanced at 66.
//  Kept from round 1: XOR-swizzled stride-64 LDS (conflict floor), defer-max.
//  New: global_load_lds staging with PRE-SWIZZLED per-lane global addresses
//  (LDS dest linear, source carries the XOR) -> no staging regs/ds_writes.
// ---------------------------------------------------------------------------
__global__ __launch_bounds__(256, 4) void attn_mfma(
    const bf16_t* __restrict__ qg,
    const bf16_t* __restrict__ kg,
    const bf16_t* __restrict__ vtg,
    bf16_t* __restrict__ og)
{
    __shared__ __align__(16) bf16_t Ks[2][4096];   // [64 k][64 d] swizzled
    __shared__ __align__(16) bf16_t Vs[2][4096];   // [64 d][64 k] swizzled
    __shared__ __align__(16) bf16_t Ps[4][1024];   // [wave][16 q][64 k] swizzled

    const int tid  = threadIdx.x;          // 0..255
    const int wave = tid >> 6;             // 0..3
    const int lane = tid & 63;
    const int l16  = lane & 15;
    const int quad = lane >> 4;

    // grid: i&7 = XCD; per XCD 4 bh x 32 q-tiles; serpentine over bh parity so
    // CU c's four resident blocks have tiles {c, 31-c, c, 31-c} -> 66 iters/CU
    const int i   = blockIdx.x;            // 0..1023
    const int xcd = i & 7;
    const int j   = i >> 3;                // 0..127
    const int bhl = j >> 5;                // 0..3
    const int u   = j & 31;
    const int q64 = (bhl & 1) ? (31 - u) : u;
    const int bh  = xcd * 4 + bhl;
    const int b = bh >> 4, hh = bh & 15;

    const char* Kb = (const char*)(kg  + (size_t)bh * 2048 * 64);
    const char* Vb = (const char*)(vtg + (size_t)bh * 64 * 2048);

    const int qglb = q64 * 64 + wave * 16 + l16;   // this lane's Q row

    const int sw  = (l16 & 7) << 4;        // XOR swizzle for rows == l16 (mod 8)
    const int cb0 = (quad << 4) ^ sw;      // frag read col byte (first 64B half)

    // staging geometry: 256 threads x 16B x 2 = one 8KB tile (K and V each);
    // LDS dest linear (tid*16), global source pre-swizzled
    const int grow = tid >> 3;                               // 0..31
    const int gsw  = ((tid & 7) << 4) ^ ((grow & 7) << 4);   // swizzled col byte

    // Q B-frags; fold 1/8 * log2(e) (softmax runs in exp2 domain)
    const bf16_t* qrow = qg + ((size_t)bh * 2048 + qglb) * 64;
    v8bf qf[2];
    qf[0] = *(const v8bf*)(qrow + quad * 8);
    qf[1] = *(const v8bf*)(qrow + 32 + quad * 8);
    #pragma unroll
    for (int e = 0; e < 8; ++e) {
        qf[0][e] = (bf16_t)((float)qf[0][e] * 0.18033688011112042f);
        qf[1][e] = (bf16_t)((float)qf[1][e] * 0.18033688011112042f);
    }

    // all-ones A-frag for the l-sum MFMA
    v8bf ones1;
    #pragma unroll
    for (int e = 0; e < 8; ++e) ones1[e] = (bf16_t)1.0f;

    float m_r = -1e30f;
    v4f l_acc = (v4f)(0.0f);               // all 4 regs hold the same l value
    v4f o_acc[4];
    #pragma unroll
    for (int d = 0; d < 4; ++d) o_acc[d] = (v4f)(0.0f);

    // stage tile 0 into buffer 0 (async; first barrier drains vmcnt)
    {
        const char* ks = Kb + ((size_t)grow << 7) + gsw;
        const char* vs = Vb + ((size_t)grow << 12) + gsw;
        char* kd = (char*)Ks[0] + tid * 16;
        char* vd = (char*)Vs[0] + tid * 16;
        load_lds16b(ks, kd);
        load_lds16b(ks + (32 << 7), kd + 4096);
        load_lds16b(vs, vd);
        load_lds16b(vs + ((size_t)32 << 12), vd + 4096);
    }

    for (int kt = 0; kt <= q64; ++kt) {
        const int cur = kt & 1;
        const int nxt = cur ^ 1;
        __syncthreads();   // buf[cur] loads drained; prior reads of buf[nxt] done

        // issue async prefetch of tile kt+1 into buf[nxt] (completes under MFMA)
        if (kt < q64) {
            const char* ks = Kb + ((size_t)((kt + 1) * 64 + grow) << 7) + gsw;
            const char* vs = Vb + ((size_t)grow << 12) + ((size_t)(kt + 1) << 7) + gsw;
            char* kd = (char*)Ks[nxt] + tid * 16;
            char* vd = (char*)Vs[nxt] + tid * 16;
            load_lds16b(ks, kd);
            load_lds16b(ks + (32 << 7), kd + 4096);
            load_lds16b(vs, vd);
            load_lds16b(vs + ((size_t)32 << 12), vd + 4096);
        }

        // ---- S^T tile ----
        const char* ksc = (const char*)Ks[cur];
        v4f s_acc[4];
        #pragma unroll
        for (int kblk = 0; kblk < 4; ++kblk) s_acc[kblk] = (v4f)(0.0f);
        #pragma unroll
        for (int kblk = 0; kblk < 4; ++kblk) {
            const char* kr = ksc + ((kblk * 16 + l16) << 7);
            const v8bf kf0 = *(const v8bf*)(kr + cb0);
            const v8bf kf1 = *(const v8bf*)(kr + (cb0 ^ 64));
            s_acc[kblk] = __builtin_amdgcn_mfma_f32_16x16x32_bf16(
                kf0, qf[0], s_acc[kblk], 0, 0, 0);
            s_acc[kblk] = __builtin_amdgcn_mfma_f32_16x16x32_bf16(
                kf1, qf[1], s_acc[kblk], 0, 0, 0);
        }

        if (kt == q64) {   // causal mask only on the diagonal (= last) tile
            #pragma unroll
            for (int kblk = 0; kblk < 4; ++kblk)
                #pragma unroll
                for (int r = 0; r < 4; ++r)
                    if (kt * 64 + kblk * 16 + quad * 4 + r > qglb)
                        s_acc[kblk][r] = -1e30f;
        }

        // ---- online softmax max (exp2 domain), defer-max rescale ----
        float mx = -1e30f;
        #pragma unroll
        for (int kblk = 0; kblk < 4; ++kblk)
            #pragma unroll
            for (int r = 0; r < 4; ++r) mx = fmaxf(mx, s_acc[kblk][r]);
        mx = fmaxf(mx, __shfl_xor(mx, 16));
        mx = fmaxf(mx, __shfl_xor(mx, 32));
        if (!__all(mx - m_r <= 8.0f)) {
            const float mn = fmaxf(m_r, mx);
            const float a  = exp2f(m_r - mn);
            m_r = mn;
            l_acc *= a;
            #pragma unroll
            for (int d = 0; d < 4; ++d) o_acc[d] *= a;
        }

        // ---- P -> Ps[wave] (swizzled), then P-frags ----
        char* psc = (char*)Ps[wave] + (l16 << 7);
        #pragma unroll
        for (int kblk = 0; kblk < 4; ++kblk) {
            v4bf p;
            #pragma unroll
            for (int r = 0; r < 4; ++r)
                p[r] = (bf16_t)exp2f(s_acc[kblk][r] - m_r);
            *(v4bf*)(psc + ((kblk * 32 + quad * 8) ^ sw)) = p;
        }
        const v8bf pf0 = *(const v8bf*)(psc + cb0);
        const v8bf pf1 = *(const v8bf*)(psc + (cb0 ^ 64));

        // ---- O^T += V^T P^T; l += ones * P^T (2 extra MFMAs) ----
        const char* vsc = (const char*)Vs[cur];
        #pragma unroll
        for (int dblk = 0; dblk < 4; ++dblk) {
            const char* vr = vsc + ((dblk * 16 + l16) << 7);
            const v8bf vf0 = *(const v8bf*)(vr + cb0);
            const v8bf vf1 = *(const v8bf*)(vr + (cb0 ^ 64));
            o_acc[dblk] = __builtin_amdgcn_mfma_f32_16x16x32_bf16(
                vf0, pf0, o_acc[dblk], 0, 0, 0);
            o_acc[dblk] = __builtin_amdgcn_mfma_f32_16x16x32_bf16(
                vf1, pf1, o_acc[dblk], 0, 0, 0);
        }
        l_acc = __builtin_amdgcn_mfma_f32_16x16x32_bf16(ones1, pf0, l_acc, 0, 0, 0);
        l_acc = __builtin_amdgcn_mfma_f32_16x16x32_bf16(ones1, pf1, l_acc, 0, 0, 0);
    }

    // ---- epilogue: O^T col m=l16 -> og[b][t][hh*64+d], v4bf stores ----
    const float inv_l = 1.0f / l_acc[0];   // all regs equal (ones-A rows)
    const size_t base = ((size_t)b * 2048 + qglb) * 1024 + hh * 64;
    #pragma unroll
    for (int dblk = 0; dblk < 4; ++dblk) {
        v4bf o;
        #pragma unroll
        for (int r = 0; r < 4; ++r) o[r] = (bf16_t)(o_acc[dblk][r] * inv_l);
        *(v4bf*)(og + base + dblk * 16 + quad * 4) = o;
    }
}

// ---------------------------------------------------------------------------
// Kernel 3: d_out(fp32) = og @ wo^T. 128x64 tiles, 512 blocks (2/CU).
// ---------------------------------------------------------------------------
__global__ __launch_bounds__(256) void out_gemm(
    const bf16_t* __restrict__ A,   // og [4096][1024] bf16
    const bf16_t* __restrict__ W,   // wob [1024][1024] bf16
    float* __restrict__ C)
{
    __shared__ __align__(16) float smemf[4352];
    bf16_t* As = (bf16_t*)smemf;        // [128][32]
    bf16_t* Bs = As + 4096;             // [64][32]

    const int tid = threadIdx.x;
    const int n0  = blockIdx.x * 64;
    const int m0  = blockIdx.y * 128;

    const int wave = tid >> 6;
    const int lane = tid & 63;
    const int l16  = lane & 15;
    const int quad = lane >> 4;
    const int wrow = (wave >> 1) * 64;
    const int wcol = (wave & 1) * 32;

    v4f acc[4][2];
    #pragma unroll
    for (int i = 0; i < 4; ++i)
        #pragma unroll
        for (int j = 0; j < 2; ++j) acc[i][j] = (v4f)(0.0f);

    for (int kt = 0; kt < 32; ++kt) {
        const int k0 = kt * 32;
        #pragma unroll
        for (int rep = 0; rep < 2; ++rep) {
            const int c   = rep * 256 + tid;
            const int row = c >> 2;
            const int col = (c & 3) * 8;
            load_lds16(A + (size_t)(m0 + row) * 1024 + k0 + col, &As[c * 8]);
        }
        {
            const int row = tid >> 2;
            const int col = (tid & 3) * 8;
            load_lds16(W + (size_t)(n0 + row) * 1024 + k0 + col, &Bs[tid * 8]);
        }
        __syncthreads();

        v8bf af[4], bfb[2];
        #pragma unroll
        for (int i = 0; i < 4; ++i)
            af[i]  = *(const v8bf*)&As[(wrow + i * 16 + l16) * 32 + quad * 8];
        #pragma unroll
        for (int j = 0; j < 2; ++j)
            bfb[j] = *(const v8bf*)&Bs[(wcol + j * 16 + l16) * 32 + quad * 8];
        #pragma unroll
        for (int i = 0; i < 4; ++i)
            #pragma unroll
            for (int j = 0; j < 2; ++j)
                acc[i][j] = __builtin_amdgcn_mfma_f32_16x16x32_bf16(
                    af[i], bfb[j], acc[i][j], 0, 0, 0);
        __syncthreads();
    }

    float* Lw = smemf + wave * 1088;
    #pragma unroll
    for (int half = 0; half < 2; ++half) {
        #pragma unroll
        for (int ii = 0; ii < 2; ++ii) {
            const int i = half * 2 + ii;
            #pragma unroll
            for (int j = 0; j < 2; ++j)
                #pragma unroll
                for (int r = 0; r < 4; ++r)
                    Lw[(ii * 16 + quad * 4 + r) * 34 + j * 16 + l16] = acc[i][j][r];
        }
        // same-wave LDS RAW: DS pipe in-order per wave
        #pragma unroll
        for (int s = 0; s < 8; ++s) {
            const int row = s * 4 + (lane >> 4);      // 0..31
            const float2 vv = *(const float2*)&Lw[row * 34 + l16 * 2];
            *(float2*)(C + (size_t)(m0 + wrow + half * 32 + row) * 1024
                         + n0 + wcol + l16 * 2) = vv;
        }
    }
}

// ---------------------------------------------------------------------------
extern "C" void kernel_launch(void* const* d_in, const int* in_sizes, int n_in,
                              void* d_out, int out_size, void* d_ws, size_t ws_size,
                              hipStream_t stream) {
    const float* h  = (const float*)d_in[0];
    const float* wq = (const float*)d_in[1];
    const float* wk = (const float*)d_in[2];
    const float* wv = (const float*)d_in[3];
    const float* wo = (const float*)d_in[4];

    const size_t NH = (size_t)4096 * 1024;   // 4M
    const size_t NW = (size_t)1024 * 1024;   // 1M

    bf16_t* hb  = (bf16_t*)d_ws;
    bf16_t* wqb = hb  + NH;
    bf16_t* wkb = wqb + NW;
    bf16_t* wvb = wkb + NW;
    bf16_t* wob = wvb + NW;
    bf16_t* qw  = wob + NW;                  // [32][2048][64]
    bf16_t* kw  = qw + NH;
    bf16_t* vw  = kw + NH;                   // [32][64][2048] (V^T)
    bf16_t* og  = hb;                        // alias: hb dead after qkv
    // total: 20M elems = 40 MB

    cvt_fp32_bf16<<<dim3(4096), dim3(256), 0, stream>>>(
        h, wq, wk, wv, wo, hb, wqb, wkb, wvb, wob);
    qkv_gemm_rope<<<dim3(24, 32), dim3(256), 0, stream>>>(
        hb, wqb, wkb, wvb, qw, kw, vw);
    attn_mfma<<<dim3(1024), dim3(256), 0, stream>>>(qw, kw, vw, og);
    out_gemm<<<dim3(16, 32), dim3(256), 0, stream>>>(og, wob, (float*)d_out);
}

// Round 3
// 186.620 us; speedup vs baseline: 1.0272x; 1.0069x over previous
//
#include <hip/hip_runtime.h>
#include <math.h>

typedef __bf16 bf16_t;
typedef __bf16 v8bf __attribute__((ext_vector_type(8)));
typedef __bf16 v4bf __attribute__((ext_vector_type(4)));
typedef float  v4f  __attribute__((ext_vector_type(4)));

#define AS1 __attribute__((address_space(1)))
#define AS3 __attribute__((address_space(3)))

// async global->LDS 16B copy; LDS dest = wave-uniform base + lane*16
static __device__ __forceinline__ void load_lds16(const bf16_t* g, bf16_t* l) {
    __builtin_amdgcn_global_load_lds((AS1 void*)const_cast<bf16_t*>(g),
                                     (AS3 void*)l, 16, 0, 0);
}
static __device__ __forceinline__ void load_lds16b(const char* g, char* l) {
    __builtin_amdgcn_global_load_lds((AS1 void*)const_cast<char*>(g),
                                     (AS3 void*)l, 16, 0, 0);
}

// sin/cos via native HW ops with explicit revolution reduction (no libcall)
static __device__ __forceinline__ void fast_sincos(float ang, float* sn, float* cs) {
    float rv = ang * 0.15915494309189535f;
    rv -= floorf(rv);
    const float a = rv * 6.283185307179586f;
    *sn = __sinf(a);
    *cs = __cosf(a);
}

// ---------------------------------------------------------------------------
// Kernel 0: fp32 -> bf16 for h + 4 weights. 8M elems, 8/thread.
// ---------------------------------------------------------------------------
__global__ __launch_bounds__(256) void cvt_fp32_bf16(
    const float* __restrict__ h,  const float* __restrict__ wq,
    const float* __restrict__ wk, const float* __restrict__ wv,
    const float* __restrict__ wo,
    bf16_t* __restrict__ hb,  bf16_t* __restrict__ wqb,
    bf16_t* __restrict__ wkb, bf16_t* __restrict__ wvb,
    bf16_t* __restrict__ wob)
{
    const size_t HM = (size_t)4 << 20;
    const size_t i8 = ((size_t)blockIdx.x * 256 + threadIdx.x) * 8;
    const float* src; bf16_t* dst; size_t off;
    if (i8 < HM) { src = h; dst = hb; off = i8; }
    else {
        const size_t r = (i8 - HM) >> 20;
        off = (i8 - HM) & (((size_t)1 << 20) - 1);
        src = (r == 0) ? wq  : (r == 1) ? wk  : (r == 2) ? wv  : wo;
        dst = (r == 0) ? wqb : (r == 1) ? wkb : (r == 2) ? wvb : wob;
    }
    const float4 a = *(const float4*)(src + off);
    const float4 b = *(const float4*)(src + off + 4);
    v8bf o;
    o[0]=(bf16_t)a.x; o[1]=(bf16_t)a.y; o[2]=(bf16_t)a.z; o[3]=(bf16_t)a.w;
    o[4]=(bf16_t)b.x; o[5]=(bf16_t)b.y; o[6]=(bf16_t)b.z; o[7]=(bf16_t)b.w;
    *(v8bf*)(dst + off) = o;
}

// ---------------------------------------------------------------------------
// Kernel 1: QKV = h @ [wq|wk|wv]^T, fused RoPE on Q,K.
// Round-3: DOUBLE-BUFFERED K-loop (1 barrier/iter, async gload_lds prefetch
// under MFMA — same proven pattern as the attn kernel) + rotation-recurrence
// RoPE epilogue (12 sincos + 60 complex-muls per thread instead of 64 sincos).
// Q,K: [32][2048][64]; V TRANSPOSED: [32][64][2048].
// ---------------------------------------------------------------------------
__global__ __launch_bounds__(256) void qkv_gemm_rope(
    const bf16_t* __restrict__ A,   // h bf16 [4096][1024]
    const bf16_t* __restrict__ wq,
    const bf16_t* __restrict__ wk,
    const bf16_t* __restrict__ wv,
    bf16_t* __restrict__ qo, bf16_t* __restrict__ ko, bf16_t* __restrict__ vo)
{
    __shared__ __align__(16) bf16_t smem[17408];
    // dbuf carve: As[b] = smem + b*4096, Bs[b] = smem + 8192 + b*4096 (32KB)
    // epilogue Ls reuses smem (after post-loop barrier)

    const int tid = threadIdx.x;
    const int n0  = blockIdx.x * 128;
    const int m0  = blockIdx.y * 128;
    const int sel = n0 >> 10;               // 0=Q 1=K 2=V
    const bf16_t* W = (sel == 0) ? wq : (sel == 1) ? wk : wv;
    const int wr0 = n0 & 1023;

    const int wave = tid >> 6;
    const int lane = tid & 63;
    const int l16  = lane & 15;
    const int quad = lane >> 4;
    const int wrow = (wave >> 1) * 64;
    const int wcol = (wave & 1) * 64;

    v4f acc[4][4];
    #pragma unroll
    for (int i = 0; i < 4; ++i)
        #pragma unroll
        for (int j = 0; j < 4; ++j) acc[i][j] = (v4f)(0.0f);

    // staging lambda-ish: tile kt -> buffer b (4 async 16B loads/thread)
    const int c0r  = tid >> 2;          // rows covered by rep0
    const int c0c  = (tid & 3) * 8;
    #define QKV_STAGE(bbuf, ktile)                                             \
        {                                                                      \
            const int k0_ = (ktile) * 32;                                      \
            load_lds16(A + (size_t)(m0 + c0r) * 1024 + k0_ + c0c,              \
                       smem + (bbuf) * 4096 + tid * 8);                        \
            load_lds16(A + (size_t)(m0 + 64 + c0r) * 1024 + k0_ + c0c,         \
                       smem + (bbuf) * 4096 + 2048 + tid * 8);                 \
            load_lds16(W + (size_t)(wr0 + c0r) * 1024 + k0_ + c0c,             \
                       smem + 8192 + (bbuf) * 4096 + tid * 8);                 \
            load_lds16(W + (size_t)(wr0 + 64 + c0r) * 1024 + k0_ + c0c,        \
                       smem + 8192 + (bbuf) * 4096 + 2048 + tid * 8);          \
        }

    QKV_STAGE(0, 0);
    for (int kt = 0; kt < 32; ++kt) {
        const int cur = kt & 1;
        __syncthreads();                 // drains vmcnt: buf[cur] ready; prior
                                         // reads of buf[cur^1] complete
        if (kt < 31) QKV_STAGE(cur ^ 1, kt + 1);

        const bf16_t* As = smem + cur * 4096;
        const bf16_t* Bs = smem + 8192 + cur * 4096;
        v8bf af[4], bfb[4];
        #pragma unroll
        for (int i = 0; i < 4; ++i) {
            af[i]  = *(const v8bf*)&As[(wrow + i * 16 + l16) * 32 + quad * 8];
            bfb[i] = *(const v8bf*)&Bs[(wcol + i * 16 + l16) * 32 + quad * 8];
        }
        #pragma unroll
        for (int i = 0; i < 4; ++i)
            #pragma unroll
            for (int j = 0; j < 4; ++j)
                acc[i][j] = __builtin_amdgcn_mfma_f32_16x16x32_bf16(
                    af[i], bfb[j], acc[i][j], 0, 0, 0);
    }
    __syncthreads();                     // As/Bs reads done before Ls reuse
    #undef QKV_STAGE

    bf16_t* Ls = smem + wave * 4352;          // [64][stride 68]
    const int bq     = (m0 + wrow) >> 11;
    const int hd     = ((n0 + wcol) >> 6) & 15;
    const int t_base = (m0 + wrow) & 2047;

    if (sel < 2) {
        bf16_t* OUT = (sel == 0) ? qo : ko;
        // rotation-recurrence RoPE: per j (kk fixed across the pair of lanes),
        // 3 sincos seed base/step1/step16, then 4-flop complex-mul walks.
        #pragma unroll
        for (int j = 0; j < 4; ++j) {
            const int dcol = j * 16 + l16;
            const int kk   = dcol >> 1;
            const float f  = exp2f((float)kk * -0.4152410118609203f);
            float cb, sb, c1, s1, c16, s16;
            fast_sincos((float)(t_base + quad * 4) * f, &sb, &cb);
            fast_sincos(f, &s1, &c1);
            fast_sincos(16.0f * f, &s16, &c16);
            float ci = cb, si = sb;          // angle at (i=0, r=0)
            #pragma unroll
            for (int i = 0; i < 4; ++i) {
                float cr = ci, sr = si;
                #pragma unroll
                for (int r = 0; r < 4; ++r) {
                    const int mrow = i * 16 + quad * 4 + r;
                    float v = acc[i][j][r];
                    const float vp = __shfl_xor(v, 1);   // pair d^1 = lane^1
                    v = ((dcol & 1) == 0) ? (cr * v - sr * vp)
                                          : (sr * vp + cr * v);
                    Ls[mrow * 68 + dcol] = (bf16_t)v;
                    if (r < 3) {                          // advance by +1 step
                        const float cn = cr * c1 - sr * s1;
                        sr = sr * c1 + cr * s1;
                        cr = cn;
                    }
                }
                if (i < 3) {                              // advance by +16 step
                    const float cn = ci * c16 - si * s16;
                    si = si * c16 + ci * s16;
                    ci = cn;
                }
            }
        }
        #pragma unroll
        for (int s = 0; s < 8; ++s) {
            const int row = s * 8 + (lane >> 3);
            const int off = (lane & 7) * 8;
            const v8bf vv = *(const v8bf*)&Ls[row * 68 + off];
            *(v8bf*)(OUT + (((size_t)(bq * 16 + hd) * 2048) + t_base + row) * 64 + off) = vv;
        }
    } else {
        #pragma unroll
        for (int i = 0; i < 4; ++i)
            #pragma unroll
            for (int j = 0; j < 4; ++j) {
                v4bf p;
                #pragma unroll
                for (int r = 0; r < 4; ++r) p[r] = (bf16_t)acc[i][j][r];
                *(v4bf*)&Ls[(j * 16 + l16) * 68 + i * 16 + quad * 4] = p;
            }
        #pragma unroll
        for (int s = 0; s < 8; ++s) {
            const int drow = s * 8 + (lane >> 3);
            const int off  = (lane & 7) * 8;
            const v8bf vv = *(const v8bf*)&Ls[drow * 68 + off];
            *(v8bf*)(vo + (((size_t)(bq * 16 + hd) * 64) + drow) * 2048 + t_base + off) = vv;
        }
    }
}

// ---------------------------------------------------------------------------
// Kernel 2: causal flash attention — UNCHANGED from round 2 (control).
// ---------------------------------------------------------------------------
__global__ __launch_bounds__(256, 4) void attn_mfma(
    const bf16_t* __restrict__ qg,
    const bf16_t* __restrict__ kg,
    const bf16_t* __restrict__ vtg,
    bf16_t* __restrict__ og)
{
    __shared__ __align__(16) bf16_t Ks[2][4096];   // [64 k][64 d] swizzled
    __shared__ __align__(16) bf16_t Vs[2][4096];   // [64 d][64 k] swizzled
    __shared__ __align__(16) bf16_t Ps[4][1024];   // [wave][16 q][64 k] swizzled

    const int tid  = threadIdx.x;          // 0..255
    const int wave = tid >> 6;             // 0..3
    const int lane = tid & 63;
    const int l16  = lane & 15;
    const int quad = lane >> 4;

    const int i   = blockIdx.x;            // 0..1023
    const int xcd = i & 7;
    const int j   = i >> 3;                // 0..127
    const int bhl = j >> 5;                // 0..3
    const int u   = j & 31;
    const int q64 = (bhl & 1) ? (31 - u) : u;
    const int bh  = xcd * 4 + bhl;
    const int b = bh >> 4, hh = bh & 15;

    const char* Kb = (const char*)(kg  + (size_t)bh * 2048 * 64);
    const char* Vb = (const char*)(vtg + (size_t)bh * 64 * 2048);

    const int qglb = q64 * 64 + wave * 16 + l16;   // this lane's Q row

    const int sw  = (l16 & 7) << 4;        // XOR swizzle for rows == l16 (mod 8)
    const int cb0 = (quad << 4) ^ sw;      // frag read col byte (first 64B half)

    const int grow = tid >> 3;                               // 0..31
    const int gsw  = ((tid & 7) << 4) ^ ((grow & 7) << 4);   // swizzled col byte

    const bf16_t* qrow = qg + ((size_t)bh * 2048 + qglb) * 64;
    v8bf qf[2];
    qf[0] = *(const v8bf*)(qrow + quad * 8);
    qf[1] = *(const v8bf*)(qrow + 32 + quad * 8);
    #pragma unroll
    for (int e = 0; e < 8; ++e) {
        qf[0][e] = (bf16_t)((float)qf[0][e] * 0.18033688011112042f);
        qf[1][e] = (bf16_t)((float)qf[1][e] * 0.18033688011112042f);
    }

    v8bf ones1;
    #pragma unroll
    for (int e = 0; e < 8; ++e) ones1[e] = (bf16_t)1.0f;

    float m_r = -1e30f;
    v4f l_acc = (v4f)(0.0f);
    v4f o_acc[4];
    #pragma unroll
    for (int d = 0; d < 4; ++d) o_acc[d] = (v4f)(0.0f);

    {
        const char* ks = Kb + ((size_t)grow << 7) + gsw;
        const char* vs = Vb + ((size_t)grow << 12) + gsw;
        char* kd = (char*)Ks[0] + tid * 16;
        char* vd = (char*)Vs[0] + tid * 16;
        load_lds16b(ks, kd);
        load_lds16b(ks + (32 << 7), kd + 4096);
        load_lds16b(vs, vd);
        load_lds16b(vs + ((size_t)32 << 12), vd + 4096);
    }

    for (int kt = 0; kt <= q64; ++kt) {
        const int cur = kt & 1;
        const int nxt = cur ^ 1;
        __syncthreads();

        if (kt < q64) {
            const char* ks = Kb + ((size_t)((kt + 1) * 64 + grow) << 7) + gsw;
            const char* vs = Vb + ((size_t)grow << 12) + ((size_t)(kt + 1) << 7) + gsw;
            char* kd = (char*)Ks[nxt] + tid * 16;
            char* vd = (char*)Vs[nxt] + tid * 16;
            load_lds16b(ks, kd);
            load_lds16b(ks + (32 << 7), kd + 4096);
            load_lds16b(vs, vd);
            load_lds16b(vs + ((size_t)32 << 12), vd + 4096);
        }

        const char* ksc = (const char*)Ks[cur];
        v4f s_acc[4];
        #pragma unroll
        for (int kblk = 0; kblk < 4; ++kblk) s_acc[kblk] = (v4f)(0.0f);
        #pragma unroll
        for (int kblk = 0; kblk < 4; ++kblk) {
            const char* kr = ksc + ((kblk * 16 + l16) << 7);
            const v8bf kf0 = *(const v8bf*)(kr + cb0);
            const v8bf kf1 = *(const v8bf*)(kr + (cb0 ^ 64));
            s_acc[kblk] = __builtin_amdgcn_mfma_f32_16x16x32_bf16(
                kf0, qf[0], s_acc[kblk], 0, 0, 0);
            s_acc[kblk] = __builtin_amdgcn_mfma_f32_16x16x32_bf16(
                kf1, qf[1], s_acc[kblk], 0, 0, 0);
        }

        if (kt == q64) {
            #pragma unroll
            for (int kblk = 0; kblk < 4; ++kblk)
                #pragma unroll
                for (int r = 0; r < 4; ++r)
                    if (kt * 64 + kblk * 16 + quad * 4 + r > qglb)
                        s_acc[kblk][r] = -1e30f;
        }

        float mx = -1e30f;
        #pragma unroll
        for (int kblk = 0; kblk < 4; ++kblk)
            #pragma unroll
            for (int r = 0; r < 4; ++r) mx = fmaxf(mx, s_acc[kblk][r]);
        mx = fmaxf(mx, __shfl_xor(mx, 16));
        mx = fmaxf(mx, __shfl_xor(mx, 32));
        if (!__all(mx - m_r <= 8.0f)) {
            const float mn = fmaxf(m_r, mx);
            const float a  = exp2f(m_r - mn);
            m_r = mn;
            l_acc *= a;
            #pragma unroll
            for (int d = 0; d < 4; ++d) o_acc[d] *= a;
        }

        char* psc = (char*)Ps[wave] + (l16 << 7);
        #pragma unroll
        for (int kblk = 0; kblk < 4; ++kblk) {
            v4bf p;
            #pragma unroll
            for (int r = 0; r < 4; ++r)
                p[r] = (bf16_t)exp2f(s_acc[kblk][r] - m_r);
            *(v4bf*)(psc + ((kblk * 32 + quad * 8) ^ sw)) = p;
        }
        const v8bf pf0 = *(const v8bf*)(psc + cb0);
        const v8bf pf1 = *(const v8bf*)(psc + (cb0 ^ 64));

        const char* vsc = (const char*)Vs[cur];
        #pragma unroll
        for (int dblk = 0; dblk < 4; ++dblk) {
            const char* vr = vsc + ((dblk * 16 + l16) << 7);
            const v8bf vf0 = *(const v8bf*)(vr + cb0);
            const v8bf vf1 = *(const v8bf*)(vr + (cb0 ^ 64));
            o_acc[dblk] = __builtin_amdgcn_mfma_f32_16x16x32_bf16(
                vf0, pf0, o_acc[dblk], 0, 0, 0);
            o_acc[dblk] = __builtin_amdgcn_mfma_f32_16x16x32_bf16(
                vf1, pf1, o_acc[dblk], 0, 0, 0);
        }
        l_acc = __builtin_amdgcn_mfma_f32_16x16x32_bf16(ones1, pf0, l_acc, 0, 0, 0);
        l_acc = __builtin_amdgcn_mfma_f32_16x16x32_bf16(ones1, pf1, l_acc, 0, 0, 0);
    }

    const float inv_l = 1.0f / l_acc[0];
    const size_t base = ((size_t)b * 2048 + qglb) * 1024 + hh * 64;
    #pragma unroll
    for (int dblk = 0; dblk < 4; ++dblk) {
        v4bf o;
        #pragma unroll
        for (int r = 0; r < 4; ++r) o[r] = (bf16_t)(o_acc[dblk][r] * inv_l);
        *(v4bf*)(og + base + dblk * 16 + quad * 4) = o;
    }
}

// ---------------------------------------------------------------------------
// Kernel 3: d_out(fp32) = og @ wo^T. 128x64 tiles.
// Round-3: double-buffered K-loop (1 barrier/iter, async prefetch under MFMA).
// ---------------------------------------------------------------------------
__global__ __launch_bounds__(256) void out_gemm(
    const bf16_t* __restrict__ A,   // og [4096][1024] bf16
    const bf16_t* __restrict__ W,   // wob [1024][1024] bf16
    float* __restrict__ C)
{
    __shared__ __align__(16) float smemf[6144];   // 24KB
    // dbuf carve (bf16 elems): As[b] = +b*4096 (128x32), Bs[b] = +8192+b*2048
    bf16_t* Sb = (bf16_t*)smemf;

    const int tid = threadIdx.x;
    const int n0  = blockIdx.x * 64;
    const int m0  = blockIdx.y * 128;

    const int wave = tid >> 6;
    const int lane = tid & 63;
    const int l16  = lane & 15;
    const int quad = lane >> 4;
    const int wrow = (wave >> 1) * 64;
    const int wcol = (wave & 1) * 32;

    v4f acc[4][2];
    #pragma unroll
    for (int i = 0; i < 4; ++i)
        #pragma unroll
        for (int j = 0; j < 2; ++j) acc[i][j] = (v4f)(0.0f);

    const int c0r = tid >> 2;
    const int c0c = (tid & 3) * 8;
    #define OUT_STAGE(bbuf, ktile)                                             \
        {                                                                      \
            const int k0_ = (ktile) * 32;                                      \
            load_lds16(A + (size_t)(m0 + c0r) * 1024 + k0_ + c0c,              \
                       Sb + (bbuf) * 4096 + tid * 8);                          \
            load_lds16(A + (size_t)(m0 + 64 + c0r) * 1024 + k0_ + c0c,         \
                       Sb + (bbuf) * 4096 + 2048 + tid * 8);                   \
            load_lds16(W + (size_t)(n0 + (tid >> 2)) * 1024 + k0_ + c0c,       \
                       Sb + 8192 + (bbuf) * 2048 + tid * 8);                   \
        }

    OUT_STAGE(0, 0);
    for (int kt = 0; kt < 32; ++kt) {
        const int cur = kt & 1;
        __syncthreads();
        if (kt < 31) OUT_STAGE(cur ^ 1, kt + 1);

        const bf16_t* As = Sb + cur * 4096;
        const bf16_t* Bs = Sb + 8192 + cur * 2048;
        v8bf af[4], bfb[2];
        #pragma unroll
        for (int i = 0; i < 4; ++i)
            af[i]  = *(const v8bf*)&As[(wrow + i * 16 + l16) * 32 + quad * 8];
        #pragma unroll
        for (int j = 0; j < 2; ++j)
            bfb[j] = *(const v8bf*)&Bs[(wcol + j * 16 + l16) * 32 + quad * 8];
        #pragma unroll
        for (int i = 0; i < 4; ++i)
            #pragma unroll
            for (int j = 0; j < 2; ++j)
                acc[i][j] = __builtin_amdgcn_mfma_f32_16x16x32_bf16(
                    af[i], bfb[j], acc[i][j], 0, 0, 0);
    }
    __syncthreads();
    #undef OUT_STAGE

    float* Lw = smemf + wave * 1088;
    #pragma unroll
    for (int half = 0; half < 2; ++half) {
        #pragma unroll
        for (int ii = 0; ii < 2; ++ii) {
            const int i = half * 2 + ii;
            #pragma unroll
            for (int j = 0; j < 2; ++j)
                #pragma unroll
                for (int r = 0; r < 4; ++r)
                    Lw[(ii * 16 + quad * 4 + r) * 34 + j * 16 + l16] = acc[i][j][r];
        }
        // same-wave LDS RAW: DS pipe in-order per wave
        #pragma unroll
        for (int s = 0; s < 8; ++s) {
            const int row = s * 4 + (lane >> 4);      // 0..31
            const float2 vv = *(const float2*)&Lw[row * 34 + l16 * 2];
            *(float2*)(C + (size_t)(m0 + wrow + half * 32 + row) * 1024
                         + n0 + wcol + l16 * 2) = vv;
        }
    }
}

// ---------------------------------------------------------------------------
extern "C" void kernel_launch(void* const* d_in, const int* in_sizes, int n_in,
                              void* d_out, int out_size, void* d_ws, size_t ws_size,
                              hipStream_t stream) {
    const float* h  = (const float*)d_in[0];
    const float* wq = (const float*)d_in[1];
    const float* wk = (const float*)d_in[2];
    const float* wv = (const float*)d_in[3];
    const float* wo = (const float*)d_in[4];

    const size_t NH = (size_t)4096 * 1024;   // 4M
    const size_t NW = (size_t)1024 * 1024;   // 1M

    bf16_t* hb  = (bf16_t*)d_ws;
    bf16_t* wqb = hb  + NH;
    bf16_t* wkb = wqb + NW;
    bf16_t* wvb = wkb + NW;
    bf16_t* wob = wvb + NW;
    bf16_t* qw  = wob + NW;                  // [32][2048][64]
    bf16_t* kw  = qw + NH;
    bf16_t* vw  = kw + NH;                   // [32][64][2048] (V^T)
    bf16_t* og  = hb;                        // alias: hb dead after qkv
    // total: 20M elems = 40 MB

    cvt_fp32_bf16<<<dim3(4096), dim3(256), 0, stream>>>(
        h, wq, wk, wv, wo, hb, wqb, wkb, wvb, wob);
    qkv_gemm_rope<<<dim3(24, 32), dim3(256), 0, stream>>>(
        hb, wqb, wkb, wvb, qw, kw, vw);
    attn_mfma<<<dim3(1024), dim3(256), 0, stream>>>(qw, kw, vw, og);
    out_gemm<<<dim3(16, 32), dim3(256), 0, stream>>>(og, wob, (float*)d_out);
}